// Round 4
// baseline (281.550 us; speedup 1.0000x reference)
//
#include <hip/hip_runtime.h>

#define BB   4
#define NHID 128
#define LL   1024
#define NH   10
#define HD   10
#define DD   100
#define SCALE 0.31622776601683794f   // 1/sqrt(10)

typedef float vfloat4 __attribute__((ext_vector_type(4)));  // builtin-compatible

// ---------------- K1: q projection -> k buffer (B, NH, L, HD) ----------------
__global__ __launch_bounds__(256) void k_qproj(
    const float* __restrict__ x, const float* __restrict__ wq_w,
    const float* __restrict__ wq_b, float* __restrict__ kbuf) {
  const int l  = blockIdx.x * 256 + threadIdx.x;
  const int c0 = blockIdx.y * 2;
  const int b  = blockIdx.z;
  float acc0 = wq_b[c0], acc1 = wq_b[c0 + 1];
  const float* xb = x + (size_t)b * NHID * LL + l;
  const float* w0 = wq_w + (size_t)c0 * NHID;
  const float* w1 = w0 + NHID;
  #pragma unroll 8
  for (int h = 0; h < NHID; ++h) {
    float xv = xb[(size_t)h * LL];   // coalesced across threads
    acc0 += w0[h] * xv;              // uniform -> scalar loads
    acc1 += w1[h] * xv;
  }
  {
    int c = c0, n = c / HD, d = c % HD;
    kbuf[(((size_t)(b * NH + n)) * LL + l) * HD + d] = acc0;
  }
  {
    int c = c0 + 1, n = c / HD, d = c % HD;
    kbuf[(((size_t)(b * NH + n)) * LL + l) * HD + d] = acc1;
  }
}

// ------- K1b: esj = exp((k.w2)*scale). The row term exp((k.w1+b)*scale)
// cancels in softmax, so si is dead code and NO per-element exp is needed. ----
__global__ __launch_bounds__(256) void k_edgeproj(
    const float* __restrict__ kbuf, const float* __restrict__ we_w,
    float* __restrict__ esj) {
  const int idx = blockIdx.x * 256 + threadIdx.x;   // over B*NH*L = 40960
  const float* kr = kbuf + (size_t)idx * HD;
  float s2 = 0.f;
  #pragma unroll
  for (int d = 0; d < HD; ++d) s2 += kr[d] * we_w[HD + d];
  esj[idx] = __expf(s2 * SCALE);
}

// ---------------- K2: fused mask + softmax + PV, exp-free inner loop --------
// alpha[i,j] = mask[i,j]*esj[j] / sum_j mask[i,j]*esj[j]
// block = 256 (4 waves) handles (b, n, 16 rows); each wave owns 4 rows.
__global__ __launch_bounds__(256) void k_attn(
    const float* __restrict__ kbuf, const float* __restrict__ esj,
    const int* __restrict__ edge,
    float* __restrict__ alpha_out, float* __restrict__ att) {
  const int t    = threadIdx.x;
  const int lane = t & 63;
  const int wid  = t >> 6;
  const int blk  = blockIdx.x;
  const int rt   = blk & 63;        // LL/16 = 64 row-tiles
  const int bn   = blk >> 6;
  const int b    = bn / NH;
  const int i0   = rt * 16 + wid * 4;

  __shared__ float ks[LL * HD];     // 40 KB: k[b,n,:,:]
  {
    const float4* src = (const float4*)(kbuf + (size_t)bn * (LL * HD));
    float4* dst = (float4*)ks;
    for (int idx = t; idx < (LL * HD) / 4; idx += 256) dst[idx] = src[idx];
  }
  // esj in two lane->j mappings: phase1 j=m*64+lane, phase2 j=m*256+lane*4
  float  esv[16];
  float4 esv4[4];
  {
    const float* sp = esj + (size_t)bn * LL;
    #pragma unroll
    for (int m = 0; m < 16; ++m) esv[m] = sp[m * 64 + lane];
    const float4* sp4 = (const float4*)sp;
    #pragma unroll
    for (int m = 0; m < 4; ++m) esv4[m] = sp4[m * 64 + lane];
  }
  __syncthreads();

  const int* ebase = edge + (size_t)b * LL * LL;

  // ---- phase 1: denominators + unnormalized PV ----
  float part[4][HD];
  float denom[4];
  #pragma unroll
  for (int r = 0; r < 4; ++r) {
    denom[r] = 0.f;
    #pragma unroll
    for (int d = 0; d < HD; ++d) part[r][d] = 0.f;
  }
  #pragma unroll
  for (int m = 0; m < 16; ++m) {
    const float* kr = ks + (m * 64 + lane) * HD;   // 4-way b64 alias: ~free
    float2 kv0 = *(const float2*)(kr + 0);
    float2 kv1 = *(const float2*)(kr + 2);
    float2 kv2 = *(const float2*)(kr + 4);
    float2 kv3 = *(const float2*)(kr + 6);
    float2 kv4 = *(const float2*)(kr + 8);
    const float es = esv[m];
    #pragma unroll
    for (int r = 0; r < 4; ++r) {
      int e = ebase[(size_t)(i0 + r) * LL + m * 64 + lane];   // coalesced
      float au = e ? es : 0.f;
      denom[r] += au;
      part[r][0] += au * kv0.x; part[r][1] += au * kv0.y;
      part[r][2] += au * kv1.x; part[r][3] += au * kv1.y;
      part[r][4] += au * kv2.x; part[r][5] += au * kv2.y;
      part[r][6] += au * kv3.x; part[r][7] += au * kv3.y;
      part[r][8] += au * kv4.x; part[r][9] += au * kv4.y;
    }
  }
  float inv[4];
  #pragma unroll
  for (int r = 0; r < 4; ++r) {
    float s = denom[r];
    #pragma unroll
    for (int sft = 32; sft >= 1; sft >>= 1) s += __shfl_xor(s, sft, 64);
    inv[r] = __builtin_amdgcn_rcpf(s);
  }

  // ---- phase 2: alpha stores (dwordx4, nontemporal; edge reload = L2 hit) ----
  float* ap = alpha_out + ((size_t)bn * LL + i0) * LL;
  #pragma unroll
  for (int m = 0; m < 4; ++m) {
    #pragma unroll
    for (int r = 0; r < 4; ++r) {
      int4 e = ((const int4*)(ebase + (size_t)(i0 + r) * LL))[m * 64 + lane];
      vfloat4 a;
      a.x = e.x ? esv4[m].x * inv[r] : 0.f;
      a.y = e.y ? esv4[m].y * inv[r] : 0.f;
      a.z = e.z ? esv4[m].z * inv[r] : 0.f;
      a.w = e.w ? esv4[m].w * inv[r] : 0.f;
      vfloat4* dst = (vfloat4*)(ap + (size_t)r * LL) + m * 64 + lane;
      __builtin_nontemporal_store(a, dst);
    }
  }

  // ---- PV reduce-scatter: 17 shuffles per row (values padded to 16) ----
  const bool b5 = (lane & 32) != 0;
  const bool b4 = (lane & 16) != 0;
  const bool b3 = (lane & 8) != 0;
  const bool b2 = (lane & 4) != 0;
  #pragma unroll
  for (int r = 0; r < 4; ++r) {
    float pv[16];
    #pragma unroll
    for (int d = 0; d < HD; ++d) pv[d] = part[r][d];
    #pragma unroll
    for (int d = HD; d < 16; ++d) pv[d] = 0.f;
    #pragma unroll
    for (int i = 0; i < 8; ++i) {
      float snd = b5 ? pv[i] : pv[i + 8];
      float kp  = b5 ? pv[i + 8] : pv[i];
      pv[i] = kp + __shfl_xor(snd, 32, 64);
    }
    #pragma unroll
    for (int i = 0; i < 4; ++i) {
      float snd = b4 ? pv[i] : pv[i + 4];
      float kp  = b4 ? pv[i + 4] : pv[i];
      pv[i] = kp + __shfl_xor(snd, 16, 64);
    }
    #pragma unroll
    for (int i = 0; i < 2; ++i) {
      float snd = b3 ? pv[i] : pv[i + 2];
      float kp  = b3 ? pv[i + 2] : pv[i];
      pv[i] = kp + __shfl_xor(snd, 8, 64);
    }
    {
      float snd = b2 ? pv[0] : pv[1];
      float kp  = b2 ? pv[1] : pv[0];
      pv[0] = kp + __shfl_xor(snd, 4, 64);
    }
    pv[0] += __shfl_xor(pv[0], 2, 64);
    pv[0] += __shfl_xor(pv[0], 1, 64);
    // lane l holds total for d=(l>>2)&15; gather to lanes 0..9, 40B store
    float g = __shfl(pv[0], lane * 4, 64);
    if (lane < HD)
      att[((size_t)bn * LL + (i0 + r)) * HD + lane] = g * inv[r];
  }
}

// ---------------- K3: output projection over scrambled view ----------------
__global__ __launch_bounds__(256) void k_out(
    const float* __restrict__ att, const float* __restrict__ wo_w,
    const float* __restrict__ wo_b, float* __restrict__ ret) {
  const int l  = blockIdx.x * 256 + threadIdx.x;
  const int o0 = blockIdx.y * 4;
  const int b  = blockIdx.z;
  const float* ab = att + (size_t)b * (DD * LL);
  float acc[4];
  #pragma unroll
  for (int oo = 0; oo < 4; ++oo) acc[oo] = wo_b[o0 + oo];
  for (int c = 0; c < DD; ++c) {
    float a = ab[(size_t)c * LL + l];            // coalesced; view(B,-1,L) == linear index
    #pragma unroll
    for (int oo = 0; oo < 4; ++oo) acc[oo] += wo_w[(size_t)(o0 + oo) * DD + c] * a;
  }
  #pragma unroll
  for (int oo = 0; oo < 4; ++oo)
    ret[((size_t)b * NHID + o0 + oo) * LL + l] = acc[oo];
}

extern "C" void kernel_launch(void* const* d_in, const int* in_sizes, int n_in,
                              void* d_out, int out_size, void* d_ws, size_t ws_size,
                              hipStream_t stream) {
  (void)in_sizes; (void)n_in; (void)out_size; (void)ws_size;
  const float* x    = (const float*)d_in[0];
  const int*   edge = (const int*)d_in[1];
  const float* wq_w = (const float*)d_in[2];
  const float* wq_b = (const float*)d_in[3];
  const float* we_w = (const float*)d_in[4];
  const float* wo_w = (const float*)d_in[6];
  const float* wo_b = (const float*)d_in[7];

  float* out       = (float*)d_out;
  float* ret_out   = out;                                  // B*NHID*L
  float* alpha_out = out + (size_t)BB * NHID * LL;         // B*NH*L*L

  float* ws   = (float*)d_ws;
  float* kbuf = ws;                                        // B*NH*L*HD = 409600
  float* esj  = kbuf + (size_t)BB * NH * LL * HD;          // B*NH*L
  float* att  = esj + (size_t)BB * NH * LL;                // B*NH*L*HD

  dim3 g1(LL / 256, DD / 2, BB);
  k_qproj<<<g1, 256, 0, stream>>>(x, wq_w, wq_b, kbuf);

  k_edgeproj<<<(BB * NH * LL) / 256, 256, 0, stream>>>(kbuf, we_w, esj);

  k_attn<<<BB * NH * (LL / 16), 256, 0, stream>>>(kbuf, esj, edge, alpha_out, att);

  dim3 g3(LL / 256, NHID / 4, BB);
  k_out<<<g3, 256, 0, stream>>>(att, wo_w, wo_b, ret_out);
}

// Round 5
// 255.276 us; speedup vs baseline: 1.1029x; 1.1029x over previous
//
#include <hip/hip_runtime.h>

#define BB   4
#define NHID 128
#define LL   1024
#define NH   10
#define HD   10
#define DD   100
#define SCALE 0.31622776601683794f   // 1/sqrt(10)

typedef float vfloat4 __attribute__((ext_vector_type(4)));

// -------- K1: q projection -> kT buffer (B, NH, HD, L) (transposed) --------
__global__ __launch_bounds__(256) void k_qproj(
    const float* __restrict__ x, const float* __restrict__ wq_w,
    const float* __restrict__ wq_b, float* __restrict__ kT) {
  const int l  = blockIdx.x * 256 + threadIdx.x;
  const int c0 = blockIdx.y * 2;
  const int b  = blockIdx.z;
  float acc0 = wq_b[c0], acc1 = wq_b[c0 + 1];
  const float* xb = x + (size_t)b * NHID * LL + l;
  const float* w0 = wq_w + (size_t)c0 * NHID;
  const float* w1 = w0 + NHID;
  #pragma unroll 8
  for (int h = 0; h < NHID; ++h) {
    float xv = xb[(size_t)h * LL];   // coalesced across threads
    acc0 += w0[h] * xv;              // uniform -> scalar loads
    acc1 += w1[h] * xv;
  }
  {
    int c = c0, n = c / HD, d = c % HD;
    kT[(((size_t)(b * NH + n)) * HD + d) * LL + l] = acc0;  // coalesced
  }
  {
    int c = c0 + 1, n = c / HD, d = c % HD;
    kT[(((size_t)(b * NH + n)) * HD + d) * LL + l] = acc1;
  }
}

// ---- K1b: esj = exp((k.w2)*scale); row factor exp(si) cancels in softmax ----
__global__ __launch_bounds__(256) void k_edgeproj(
    const float* __restrict__ kT, const float* __restrict__ we_w,
    float* __restrict__ esj) {
  const int idx = blockIdx.x * 256 + threadIdx.x;   // over B*NH*L = 40960
  const int bn = idx >> 10, l = idx & (LL - 1);
  const float* kp = kT + (size_t)bn * HD * LL + l;
  float s2 = 0.f;
  #pragma unroll
  for (int d = 0; d < HD; ++d) s2 += kp[(size_t)d * LL] * we_w[HD + d];  // coalesced
  esj[idx] = __expf(s2 * SCALE);
}

// ------------- K2: fused mask + softmax + PV, exp-free, single edge pass ----
// alpha[i,j] = mask[i,j]*esj[j] / sum_j mask[i,j]*esj[j]
// block = 512 (8 waves) handles (b, n, 32 rows); each wave owns 4 rows.
// j-mapping (all phases): j = m*256 + lane*4 + q, m=0..3, q=0..3.
__global__ __launch_bounds__(512) void k_attn(
    const float* __restrict__ kT, const float* __restrict__ esj,
    const int* __restrict__ edge,
    float* __restrict__ alpha_out, float* __restrict__ att) {
  const int t    = threadIdx.x;
  const int lane = t & 63;
  const int wid  = t >> 6;
  const int blk  = blockIdx.x;
  const int rt   = blk & 31;        // LL/32 = 32 row-tiles
  const int bn   = blk >> 5;
  const int b    = bn / NH;
  const int i0   = rt * 32 + wid * 4;

  __shared__ float ksT[HD * LL];    // 40 KB: kT[b,n,:,:] (d-major, stride-1 in j)
  {
    const float4* src = (const float4*)(kT + (size_t)bn * (HD * LL));
    float4* dst = (float4*)ksT;
    #pragma unroll
    for (int idx = t; idx < (HD * LL) / 4; idx += 512) dst[idx] = src[idx];
  }
  vfloat4 esv[4];
  {
    const vfloat4* sp = (const vfloat4*)(esj + (size_t)bn * LL);
    #pragma unroll
    for (int m = 0; m < 4; ++m) esv[m] = sp[m * 64 + lane];
  }
  __syncthreads();

  const int* ebase = edge + (size_t)b * LL * LL + (size_t)i0 * LL;

  // ---- phase 1: edge (once, int4), denom, unnormalized PV; keep mask bits ----
  float part[4][HD];
  float denom[4];
  unsigned mask[4];
  #pragma unroll
  for (int r = 0; r < 4; ++r) {
    denom[r] = 0.f; mask[r] = 0u;
    #pragma unroll
    for (int d = 0; d < HD; ++d) part[r][d] = 0.f;
  }
  #pragma unroll
  for (int m = 0; m < 4; ++m) {
    // k[j..j+3][d] for all d: 10 conflict-free ds_read_b128, shared by 4 rows
    vfloat4 kv[HD];
    const float* kb = ksT + m * 256 + lane * 4;
    #pragma unroll
    for (int d = 0; d < HD; ++d) kv[d] = *(const vfloat4*)(kb + d * LL);
    const vfloat4 es = esv[m];
    #pragma unroll
    for (int r = 0; r < 4; ++r) {
      int4 e = ((const int4*)(ebase + (size_t)r * LL))[m * 64 + lane];  // coalesced x4
      float ax = e.x ? es.x : 0.f;
      float ay = e.y ? es.y : 0.f;
      float az = e.z ? es.z : 0.f;
      float aw = e.w ? es.w : 0.f;
      mask[r] |= ((e.x ? 1u : 0u) | (e.y ? 2u : 0u) | (e.z ? 4u : 0u) | (e.w ? 8u : 0u)) << (m * 4);
      denom[r] += (ax + ay) + (az + aw);
      #pragma unroll
      for (int d = 0; d < HD; ++d)
        part[r][d] += ax * kv[d].x + ay * kv[d].y + az * kv[d].z + aw * kv[d].w;
    }
  }
  float inv[4];
  #pragma unroll
  for (int r = 0; r < 4; ++r) {
    float s = denom[r];
    #pragma unroll
    for (int sft = 32; sft >= 1; sft >>= 1) s += __shfl_xor(s, sft, 64);
    inv[r] = __builtin_amdgcn_rcpf(s);
  }

  // ---- phase 2: alpha stores from mask bits (no global reload) ----
  float* ap = alpha_out + ((size_t)bn * LL + i0) * LL;
  #pragma unroll
  for (int m = 0; m < 4; ++m) {
    const vfloat4 es = esv[m];
    #pragma unroll
    for (int r = 0; r < 4; ++r) {
      const unsigned mk = mask[r] >> (m * 4);
      vfloat4 a;
      a.x = (mk & 1u) ? es.x * inv[r] : 0.f;
      a.y = (mk & 2u) ? es.y * inv[r] : 0.f;
      a.z = (mk & 4u) ? es.z * inv[r] : 0.f;
      a.w = (mk & 8u) ? es.w * inv[r] : 0.f;
      vfloat4* dst = (vfloat4*)(ap + (size_t)r * LL) + m * 64 + lane;
      __builtin_nontemporal_store(a, dst);
    }
  }

  // ---- PV reduce-scatter: 17 shuffles per row (values padded to 16) ----
  const bool b5 = (lane & 32) != 0;
  const bool b4 = (lane & 16) != 0;
  const bool b3 = (lane & 8) != 0;
  const bool b2 = (lane & 4) != 0;
  #pragma unroll
  for (int r = 0; r < 4; ++r) {
    float pv[16];
    #pragma unroll
    for (int d = 0; d < HD; ++d) pv[d] = part[r][d];
    #pragma unroll
    for (int d = HD; d < 16; ++d) pv[d] = 0.f;
    #pragma unroll
    for (int i = 0; i < 8; ++i) {
      float snd = b5 ? pv[i] : pv[i + 8];
      float kp  = b5 ? pv[i + 8] : pv[i];
      pv[i] = kp + __shfl_xor(snd, 32, 64);
    }
    #pragma unroll
    for (int i = 0; i < 4; ++i) {
      float snd = b4 ? pv[i] : pv[i + 4];
      float kp  = b4 ? pv[i + 4] : pv[i];
      pv[i] = kp + __shfl_xor(snd, 16, 64);
    }
    #pragma unroll
    for (int i = 0; i < 2; ++i) {
      float snd = b3 ? pv[i] : pv[i + 2];
      float kp  = b3 ? pv[i + 2] : pv[i];
      pv[i] = kp + __shfl_xor(snd, 8, 64);
    }
    {
      float snd = b2 ? pv[0] : pv[1];
      float kp  = b2 ? pv[1] : pv[0];
      pv[0] = kp + __shfl_xor(snd, 4, 64);
    }
    pv[0] += __shfl_xor(pv[0], 2, 64);
    pv[0] += __shfl_xor(pv[0], 1, 64);
    // lane l holds total for d=(l>>2)&15; gather to lanes 0..9, 40B store
    float g = __shfl(pv[0], lane * 4, 64);
    if (lane < HD)
      att[((size_t)bn * LL + (i0 + r)) * HD + lane] = g * inv[r];
  }
}

// ---------------- K3: output projection over scrambled view ----------------
__global__ __launch_bounds__(256) void k_out(
    const float* __restrict__ att, const float* __restrict__ wo_w,
    const float* __restrict__ wo_b, float* __restrict__ ret) {
  const int l  = blockIdx.x * 256 + threadIdx.x;
  const int o0 = blockIdx.y * 4;
  const int b  = blockIdx.z;
  const float* ab = att + (size_t)b * (DD * LL);
  float acc[4];
  #pragma unroll
  for (int oo = 0; oo < 4; ++oo) acc[oo] = wo_b[o0 + oo];
  for (int c = 0; c < DD; ++c) {
    float a = ab[(size_t)c * LL + l];            // coalesced; view(B,-1,L) == linear index
    #pragma unroll
    for (int oo = 0; oo < 4; ++oo) acc[oo] += wo_w[(size_t)(o0 + oo) * DD + c] * a;
  }
  #pragma unroll
  for (int oo = 0; oo < 4; ++oo)
    ret[((size_t)b * NHID + o0 + oo) * LL + l] = acc[oo];
}

extern "C" void kernel_launch(void* const* d_in, const int* in_sizes, int n_in,
                              void* d_out, int out_size, void* d_ws, size_t ws_size,
                              hipStream_t stream) {
  (void)in_sizes; (void)n_in; (void)out_size; (void)ws_size;
  const float* x    = (const float*)d_in[0];
  const int*   edge = (const int*)d_in[1];
  const float* wq_w = (const float*)d_in[2];
  const float* wq_b = (const float*)d_in[3];
  const float* we_w = (const float*)d_in[4];
  const float* wo_w = (const float*)d_in[6];
  const float* wo_b = (const float*)d_in[7];

  float* out       = (float*)d_out;
  float* ret_out   = out;                                  // B*NHID*L
  float* alpha_out = out + (size_t)BB * NHID * LL;         // B*NH*L*L

  float* ws   = (float*)d_ws;
  float* kT   = ws;                                        // B*NH*HD*L = 409600
  float* esj  = kT + (size_t)BB * NH * HD * LL;            // B*NH*L
  float* att  = esj + (size_t)BB * NH * LL;                // B*NH*L*HD

  dim3 g1(LL / 256, DD / 2, BB);
  k_qproj<<<g1, 256, 0, stream>>>(x, wq_w, wq_b, kT);

  k_edgeproj<<<(BB * NH * LL) / 256, 256, 0, stream>>>(kT, we_w, esj);

  k_attn<<<BB * NH * (LL / 32), 512, 0, stream>>>(kT, esj, edge, alpha_out, att);

  dim3 g3(LL / 256, NHID / 4, BB);
  k_out<<<g3, 256, 0, stream>>>(att, wo_w, wo_b, ret_out);
}